// Round 12
// baseline (25.999 us; speedup 1.0000x reference)
//
#include <hip/hip_runtime.h>
#include <math.h>

#define IMG 256
#define NB 64
#define NCH 8
#define NROWS (NB * IMG)   // 16384 (b,h) rows
#define PLANE (IMG * IMG)  // 65536

typedef float vf4 __attribute__((ext_vector_type(4)));
typedef float vf2 __attribute__((ext_vector_type(2)));

// Area table for s in [64,256], passed by value (kernarg segment).
struct TabArg { int a[193]; };

// ---------- device helpers ----------

// floor(sqrt(x)) for 0 <= x <= 65535, exact via f32 sqrt + +/-1 correction
__device__ __forceinline__ int isqrt_i(int x) {
    int t = (int)__builtin_sqrtf((float)x);
    t -= (t * t > x);
    t += ((t + 1) * (t + 1) <= x);
    return t;
}

// Closed-form row interval count. mask(b,h,w) <=> (2w-255)^2 + (2h-255)^2 < s^2
// (exact integer equivalence with the reference's f32 sqrt comparison).
// cnt is even; interval is [lo, 255-lo] with lo = (255 - (cnt-1))/2.
__device__ __forceinline__ int row_count(int s, int h) {
    int ky = 2 * h - 255;
    int rem = s * s - ky * ky;
    if (rem < 2) return 0;             // need kx^2 < rem with kx odd >= 1
    int t = isqrt_i(rem - 1);          // largest t with t^2 < rem
    int kx_max = (t & 1) ? t : t - 1;  // kx = 255-2w is odd
    return kx_max + 1;
}

// ---------- single fused kernel ----------
// 4 rows per 1024-thread block (grid 4096: tests CP dispatch-rate hypothesis).
// Wave-autonomous: each 64-lane wave owns a 64-px slice of one row; no LDS,
// no barriers. Prefix n0 is reduced per-wave (redundantly) via shfl.
__global__ void __launch_bounds__(1024) fused_scatter(
        const float* __restrict__ batch,
        const int* __restrict__ sizes,
        float* __restrict__ out, int N, int out_size, TabArg tab) {
    int t = threadIdx.x & 255;            // w coordinate
    int row = blockIdx.x * 4 + (threadIdx.x >> 8);
    if (row == 0 && threadIdx.x == 0) out[out_size - 1] = (float)NB;  // batch_size

    int b = row >> 8;
    int h = row & 255;
    int s = sizes[b];                     // wave-uniform scalar load
    int cnt = row_count(s, h);            // uniform
    if (cnt == 0) return;                 // uniform exit (~38% of rows)
    int lo = (255 - (cnt - 1)) >> 1;
    int hi = lo + cnt;

    // wave-slice early exit: this wave covers w in [wbase, wbase+64)
    int wbase = t & ~63;
    if (wbase + 63 < lo || wbase >= hi) return;   // wave-uniform

    // unconditional channel loads (w always in-bounds of the full image row);
    // issued before the prefix VALU work so latency hides under it
    const float* bp = batch + (size_t)b * NCH * PLANE + h * IMG + t;
    float c0 = bp[0 * PLANE], c1 = bp[1 * PLANE], c2 = bp[2 * PLANE],
          c3 = bp[3 * PLANE], c4 = bp[4 * PLANE], c5 = bp[5 * PLANE],
          c6 = bp[6 * PLANE], c7 = bp[7 * PLANE];

    // per-wave combined prefix: cross-image base + in-image row prefix
    int L = t & 63;
    int v = (L < b) ? tab.a[sizes[L] - 64] : 0;
    #pragma unroll
    for (int k = 0; k < 4; ++k) {
        int hp = L + k * 64;
        v += (hp < h) ? row_count(s, hp) : 0;
    }
    #pragma unroll
    for (int o = 32; o; o >>= 1) v += __shfl_down(v, o);
    int n0 = __shfl(v, 0);                // broadcast wave-sum

    if (t < lo || t >= hi) return;
    int n = n0 + (t - lo);

    vf4 t0, t1;
    t0.x = c0; t0.y = c1; t0.z = c2; t0.w = c3;
    t1.x = c4; t1.y = c5; t1.z = c6; t1.w = c7;
    *(vf4*)(out + (size_t)n * 8) = t0;    // 32B-aligned
    *(vf4*)(out + (size_t)n * 8 + 4) = t1;

    vf2 p; p.x = (float)h; p.y = (float)t;
    *(vf2*)(out + (size_t)N * 8 + (size_t)n * 2) = p;

    out[(size_t)N * 10 + n] = (float)b;
}

// ---------- host ----------

static int h_isqrt(int x) {
    int t = (int)sqrt((double)x);
    while (t * t > x) --t;
    while ((t + 1) * (t + 1) <= x) ++t;
    return t;
}

static int h_row_count(int s, int h) {
    int ky = 2 * h - 255;
    int rem = s * s - ky * ky;
    if (rem < 2) return 0;
    int t = h_isqrt(rem - 1);
    int kx_max = (t & 1) ? t : t - 1;
    return kx_max + 1;
}

extern "C" void kernel_launch(void* const* d_in, const int* in_sizes, int n_in,
                              void* d_out, int out_size, void* d_ws, size_t ws_size,
                              hipStream_t stream) {
    const float* batch = (const float*)d_in[0];
    const int* sizes = (const int*)d_in[1];
    float* out = (float*)d_out;

    // out layout: tex [N*8] | pts [N*2] | imgid [N] | batch_size [1]
    int N = (out_size - 1) / 11;

    // area(s) is a pure function of s: precomputed host-side (capture path
    // only, never in the timed replay), passed by value via kernarg
    TabArg tab;
    for (int s = 64; s <= 256; ++s) {
        int a = 0;
        for (int h = 0; h < 128; ++h) a += h_row_count(s, h);
        tab.a[s - 64] = 2 * a;   // h-symmetry: row_count(s,h) == row_count(s,255-h)
    }

    fused_scatter<<<NROWS / 4, 1024, 0, stream>>>(batch, sizes, out, N, out_size, tab);
}

// Round 13
// 24.592 us; speedup vs baseline: 1.0572x; 1.0572x over previous
//
#include <hip/hip_runtime.h>
#include <math.h>

#define IMG 256
#define NB 64
#define NCH 8
#define NROWS (NB * IMG)   // 16384 (b,h) rows
#define PLANE (IMG * IMG)  // 65536

typedef float vf4 __attribute__((ext_vector_type(4)));
typedef float vf2 __attribute__((ext_vector_type(2)));

// Area table for s in [64,256], passed by value (kernarg segment).
struct TabArg { int a[193]; };

// ---------- device helpers ----------

// floor(sqrt(x)) for 0 <= x <= 65535, exact via f32 sqrt + +/-1 correction
__device__ __forceinline__ int isqrt_i(int x) {
    int t = (int)__builtin_sqrtf((float)x);
    t -= (t * t > x);
    t += ((t + 1) * (t + 1) <= x);
    return t;
}

// Closed-form row interval count. mask(b,h,w) <=> (2w-255)^2 + (2h-255)^2 < s^2
// (exact integer equivalence with the reference's f32 sqrt comparison).
// cnt is even; interval is [lo, 255-lo] with lo = (255 - (cnt-1))/2.
__device__ __forceinline__ int row_count(int s, int h) {
    int ky = 2 * h - 255;
    int rem = s * s - ky * ky;
    if (rem < 2) return 0;             // need kx^2 < rem with kx odd >= 1
    int t = isqrt_i(rem - 1);          // largest t with t^2 < rem
    int kx_max = (t & 1) ? t : t - 1;  // kx = 255-2w is odd
    return kx_max + 1;
}

// ---------- single fused kernel (R11 + wave-slice early exit) ----------
// One block per (b,h) row, thread = w. No LDS, no barriers, single dispatch.
// Loads are exec-mask predicated (inactive lanes generate NO transactions --
// R12 made them unconditional and regressed; keep predication).
__global__ void __launch_bounds__(256) fused_scatter(
        const float* __restrict__ batch,
        const int* __restrict__ sizes,
        float* __restrict__ out, int N, int out_size, TabArg tab) {
    int row = blockIdx.x;
    int t = threadIdx.x;
    if (row == 0 && t == 0) out[out_size - 1] = (float)NB;  // batch_size

    int b = row >> 8;
    int h = row & 255;
    int s = sizes[b];                 // wave-uniform -> scalar load, L1-hot
    int cnt = row_count(s, h);        // uniform
    if (cnt == 0) return;             // uniform exit (~38% of rows)
    int lo = (255 - (cnt - 1)) >> 1;
    int hi = lo + cnt;

    // wave-uniform slice exit: this wave covers w in [wbase, wbase+64)
    int wbase = t & ~63;
    if (wbase + 63 < lo || wbase >= hi) return;

    bool act = (t >= lo) & (t < hi);

    // issue the 8 channel loads immediately (predicated, stay in flight)
    const float* bp = batch + (size_t)b * NCH * PLANE + h * IMG + t;
    float c0, c1, c2, c3, c4, c5, c6, c7;
    if (act) {
        c0 = bp[0 * PLANE]; c1 = bp[1 * PLANE]; c2 = bp[2 * PLANE];
        c3 = bp[3 * PLANE]; c4 = bp[4 * PLANE]; c5 = bp[5 * PLANE];
        c6 = bp[6 * PLANE]; c7 = bp[7 * PLANE];
    }

    // per-wave combined prefix: cross-image base + in-image row prefix
    int L = t & 63;
    int v = (L < b) ? tab.a[sizes[L] - 64] : 0;
    #pragma unroll
    for (int k = 0; k < 4; ++k) {
        int hp = L + k * 64;
        v += (hp < h) ? row_count(s, hp) : 0;
    }
    #pragma unroll
    for (int o = 32; o; o >>= 1) v += __shfl_down(v, o);
    int n0 = __shfl(v, 0);            // broadcast wave-sum

    if (!act) return;
    int n = n0 + (t - lo);

    vf4 t0, t1;
    t0.x = c0; t0.y = c1; t0.z = c2; t0.w = c3;
    t1.x = c4; t1.y = c5; t1.z = c6; t1.w = c7;
    *(vf4*)(out + (size_t)n * 8) = t0;              // 32B-aligned
    *(vf4*)(out + (size_t)n * 8 + 4) = t1;

    vf2 p; p.x = (float)h; p.y = (float)t;
    *(vf2*)(out + (size_t)N * 8 + (size_t)n * 2) = p;

    out[(size_t)N * 10 + n] = (float)b;
}

// ---------- host ----------

static int h_isqrt(int x) {
    int t = (int)sqrt((double)x);
    while (t * t > x) --t;
    while ((t + 1) * (t + 1) <= x) ++t;
    return t;
}

static int h_row_count(int s, int h) {
    int ky = 2 * h - 255;
    int rem = s * s - ky * ky;
    if (rem < 2) return 0;
    int t = h_isqrt(rem - 1);
    int kx_max = (t & 1) ? t : t - 1;
    return kx_max + 1;
}

extern "C" void kernel_launch(void* const* d_in, const int* in_sizes, int n_in,
                              void* d_out, int out_size, void* d_ws, size_t ws_size,
                              hipStream_t stream) {
    const float* batch = (const float*)d_in[0];
    const int* sizes = (const int*)d_in[1];
    float* out = (float*)d_out;

    // out layout: tex [N*8] | pts [N*2] | imgid [N] | batch_size [1]
    int N = (out_size - 1) / 11;

    // area(s) is a pure function of s: precomputed host-side (capture path
    // only, never in the timed replay), passed by value via kernarg
    TabArg tab;
    for (int s = 64; s <= 256; ++s) {
        int a = 0;
        for (int h = 0; h < 128; ++h) a += h_row_count(s, h);
        tab.a[s - 64] = 2 * a;   // h-symmetry: row_count(s,h) == row_count(s,255-h)
    }

    fused_scatter<<<NROWS, 256, 0, stream>>>(batch, sizes, out, N, out_size, tab);
}